// Round 1
// baseline (1037.682 us; speedup 1.0000x reference)
//
#include <hip/hip_runtime.h>

// Fused transformer block, one workgroup per batch element.
// ws layout (bf16/ushort elements): [0,65536) WqT[h][d][c]; [65536,131072) WkT;
// [131072,196608) WvT; [196608,262144) WprojT[n][c]; [262144,524288) W1T[n][c];
// [524288,786432) W2T[n][k].  Requires ws_size >= 1572864 bytes.

typedef float v4f __attribute__((ext_vector_type(4)));
typedef int   v4i __attribute__((ext_vector_type(4)));

#define DEV static __device__ __forceinline__

DEV unsigned short f2bf(float f){
  unsigned u = __builtin_bit_cast(unsigned, f);
  u += 0x7fffu + ((u >> 16) & 1u);
  return (unsigned short)(u >> 16);
}

// bf16 MFMA via inline asm: layout-safe under consistent per-lane contiguous-8
// K fragments (A from [M][K] rows, B from [N][K] rows i.e. pre-transposed).
DEV v4f mfma16(v4i a, v4i b, v4f c){
  asm("v_mfma_f32_16x16x32_bf16 %0, %1, %2, %0" : "+v"(c) : "v"(a), "v"(b));
  return c;
}
// Hazard fence: asm MFMA is opaque to the hazard recognizer; pad before VALU
// reads of freshly written accumulators.
DEV v4f accfence(v4f c){
  asm("s_nop 7\n\ts_nop 3" : "+v"(c));
  return c;
}

// Swizzled LDS byte offsets (G4: row-major bf16 tiles, XOR row bits into the
// 16B-granule bits so 16 rows spread over 8 bank-groups; 2-way is free).
DEV int hoff(int r, int c){ return r*512 + ((c*2) ^ ((r & 7) << 4)); }  // [64][256] bf16
DEV int koff(int r, int c){ return r*128 + ((c*2) ^ ((r & 7) << 4)); }  // [*][64]  bf16

DEV float rsum64(float v){
  #pragma unroll
  for (int k = 1; k < 64; k <<= 1) v += __shfl_xor(v, k);
  return v;
}
DEV float rsum16(float v){
  #pragma unroll
  for (int k = 1; k < 16; k <<= 1) v += __shfl_xor(v, k);
  return v;
}
DEV float rmax16(float v){
  #pragma unroll
  for (int k = 1; k < 16; k <<= 1) v = fmaxf(v, __shfl_xor(v, k));
  return v;
}

__global__ void prep_w(const float* __restrict__ Wq, const float* __restrict__ Wk,
                       const float* __restrict__ Wv, const float* __restrict__ Wp,
                       const float* __restrict__ W1, const float* __restrict__ W2,
                       unsigned short* __restrict__ ws){
  int t = blockIdx.x * 256 + threadIdx.x;   // grid covers exactly 786432
  float v;
  if (t < 196608){
    int seg = t >> 16, r = t & 65535;
    int c = r & 255, d = (r >> 8) & 63, h = r >> 14;
    const float* W = (seg == 0) ? Wq : ((seg == 1) ? Wk : Wv);
    v = W[h*16384 + c*64 + d];
  } else if (t < 262144){
    int r = t - 196608; int n = r >> 8, c = r & 255;
    v = Wp[c*256 + n];
  } else if (t < 524288){
    int r = t - 262144; int n = r >> 8, c = r & 255;
    v = W1[c*1024 + n];
  } else {
    int r = t - 524288; int n = r >> 10, k = r & 1023;
    v = W2[k*256 + n];
  }
  ws[t] = f2bf(v);
}

__global__ __launch_bounds__(256, 2) void blk_fwd(
    const float* __restrict__ x,
    const float* __restrict__ ln1g, const float* __restrict__ ln1b,
    const unsigned short* __restrict__ wqT,
    const unsigned short* __restrict__ wkT,
    const unsigned short* __restrict__ wvT,
    const unsigned short* __restrict__ wpT,
    const float* __restrict__ bpj,
    const float* __restrict__ ln2g, const float* __restrict__ ln2b,
    const unsigned short* __restrict__ w1T,
    const float* __restrict__ b1,
    const unsigned short* __restrict__ w2T,
    const float* __restrict__ b2,
    float* __restrict__ out)
{
  __shared__ char smb[65536] __attribute__((aligned(16)));
  char* sm = smb;
  // LDS map. Lower 32KB: h (phase A-B), then h2 (phase C-D), both [64][256] bf16.
  // Upper 32KB: phase B = q|k|vt ([64][64] bf16 each) + per-wave p/att stripes;
  //             phase C = LN2 partial sums; phase D = activation chunk [64][256].
  const int HLS = 0, QLS = 32768, KLS = 40960, VTLS = 49152, PATLS = 57344;
  const int ALS = 32768, PSUM = 32768, PSQ = 33792, MU2 = 34816, RS2 = 35072;

  const int b = blockIdx.x;
  const float* __restrict__ xb   = x   + (size_t)b * (64*256);
  float* __restrict__       outb = out + (size_t)b * (64*256);
  const int tid = threadIdx.x;
  const int w = tid >> 6, l = tid & 63, m = l & 15, g = l >> 4;
  const v4f zf = {0.f, 0.f, 0.f, 0.f};

  // ---------------- Phase A: LN1 -> h (bf16, LDS) ----------------
  {
    float lg[4], lb[4];
    #pragma unroll
    for (int j = 0; j < 4; ++j){ lg[j] = ln1g[l + 64*j]; lb[j] = ln1b[l + 64*j]; }
    float xv[16][4];
    #pragma unroll
    for (int rr = 0; rr < 16; ++rr){
      const float* xr = xb + (w*16 + rr)*256;
      #pragma unroll
      for (int j = 0; j < 4; ++j) xv[rr][j] = xr[l + 64*j];
    }
    #pragma unroll
    for (int rr = 0; rr < 16; ++rr){
      int r = w*16 + rr;
      float s = 0.f, q = 0.f;
      #pragma unroll
      for (int j = 0; j < 4; ++j){ s += xv[rr][j]; q += xv[rr][j]*xv[rr][j]; }
      s = rsum64(s); q = rsum64(q);
      float mu = s * (1.f/256.f);
      float rs = rsqrtf(q * (1.f/256.f) - mu*mu + 1e-6f);
      #pragma unroll
      for (int j = 0; j < 4; ++j){
        float hv = (xv[rr][j] - mu) * rs * lg[j] + lb[j];
        *(unsigned short*)(sm + HLS + hoff(r, l + 64*j)) = f2bf(hv);
      }
    }
  }
  __syncthreads();

  // ---------------- Phase B: attention; sa accumulated in regs ----------------
  v4f sa[4][4];
  #pragma unroll
  for (int i = 0; i < 4; ++i){
    #pragma unroll
    for (int j = 0; j < 4; ++j) sa[i][j] = zf;
  }

  #pragma unroll 1
  for (int hh = 0; hh < 4; ++hh){
    // QKV for head hh: wave w owns output cols w*16..w*16+15, all 64 rows.
    v4f qa[4], ka[4], va[4];
    #pragma unroll
    for (int rt = 0; rt < 4; ++rt){ qa[rt] = zf; ka[rt] = zf; va[rt] = zf; }
    const unsigned short* wq = wqT + hh*16384 + (w*16 + m)*256;
    const unsigned short* wk = wkT + hh*16384 + (w*16 + m)*256;
    const unsigned short* wv = wvT + hh*16384 + (w*16 + m)*256;
    #pragma unroll
    for (int ks = 0; ks < 8; ++ks){
      int k0 = ks*32 + 8*g;
      v4i af[4];
      #pragma unroll
      for (int rt = 0; rt < 4; ++rt) af[rt] = *(const v4i*)(sm + HLS + hoff(rt*16 + m, k0));
      v4i bq = *(const v4i*)(wq + k0);
      v4i bk = *(const v4i*)(wk + k0);
      v4i bv = *(const v4i*)(wv + k0);
      #pragma unroll
      for (int rt = 0; rt < 4; ++rt){
        qa[rt] = mfma16(af[rt], bq, qa[rt]);
        ka[rt] = mfma16(af[rt], bk, ka[rt]);
        va[rt] = mfma16(af[rt], bv, va[rt]);
      }
    }
    #pragma unroll
    for (int rt = 0; rt < 4; ++rt){
      qa[rt] = accfence(qa[rt]); ka[rt] = accfence(ka[rt]); va[rt] = accfence(va[rt]);
    }
    #pragma unroll
    for (int rt = 0; rt < 4; ++rt){
      #pragma unroll
      for (int j = 0; j < 4; ++j){
        int t = rt*16 + 4*g + j;
        *(unsigned short*)(sm + QLS + koff(t, w*16 + m)) = f2bf(qa[rt][j]);
        *(unsigned short*)(sm + KLS + koff(t, w*16 + m)) = f2bf(ka[rt][j]);
      }
      unsigned long long pk =
          (unsigned long long)f2bf(va[rt][0])
        | ((unsigned long long)f2bf(va[rt][1]) << 16)
        | ((unsigned long long)f2bf(va[rt][2]) << 32)
        | ((unsigned long long)f2bf(va[rt][3]) << 48);
      *(unsigned long long*)(sm + VTLS + koff(w*16 + m, rt*16 + 4*g)) = pk;  // V^T
    }
    __syncthreads();

    // S = Q K^T for stripe rows w*16..w*16+15
    v4f s4[4];
    #pragma unroll
    for (int nt = 0; nt < 4; ++nt) s4[nt] = zf;
    #pragma unroll
    for (int ks = 0; ks < 2; ++ks){
      int k0 = ks*32 + 8*g;
      v4i qf = *(const v4i*)(sm + QLS + koff(w*16 + m, k0));
      #pragma unroll
      for (int nt = 0; nt < 4; ++nt){
        v4i kf = *(const v4i*)(sm + KLS + koff(nt*16 + m, k0));
        s4[nt] = mfma16(qf, kf, s4[nt]);
      }
    }
    #pragma unroll
    for (int nt = 0; nt < 4; ++nt) s4[nt] = accfence(s4[nt]);

    // causal mask + softmax (rows spread over 16-lane groups; regs j = rows 4g+j)
    float mx[4] = {-3e38f, -3e38f, -3e38f, -3e38f};
    #pragma unroll
    for (int nt = 0; nt < 4; ++nt){
      #pragma unroll
      for (int j = 0; j < 4; ++j){
        int t = w*16 + 4*g + j, ss = nt*16 + m;
        float z = s4[nt][j] * 0.125f;
        z = (ss <= t) ? z : -1e30f;
        s4[nt][j] = z;
        mx[j] = fmaxf(mx[j], z);
      }
    }
    #pragma unroll
    for (int j = 0; j < 4; ++j) mx[j] = rmax16(mx[j]);
    float sum[4] = {0.f, 0.f, 0.f, 0.f};
    #pragma unroll
    for (int nt = 0; nt < 4; ++nt){
      #pragma unroll
      for (int j = 0; j < 4; ++j){
        float p = __expf(s4[nt][j] - mx[j]);
        s4[nt][j] = p;
        sum[j] += p;
      }
    }
    #pragma unroll
    for (int j = 0; j < 4; ++j) sum[j] = 1.f / rsum16(sum[j]);
    #pragma unroll
    for (int nt = 0; nt < 4; ++nt){
      #pragma unroll
      for (int j = 0; j < 4; ++j){
        *(unsigned short*)(sm + PATLS + w*2048 + koff(4*g + j, nt*16 + m)) =
            f2bf(s4[nt][j] * sum[j]);
      }
    }

    // att = P V  (B-operand = V^T rows, per-lane contiguous in t)
    v4f av[4];
    #pragma unroll
    for (int nt = 0; nt < 4; ++nt) av[nt] = zf;
    #pragma unroll
    for (int ks = 0; ks < 2; ++ks){
      int k0 = ks*32 + 8*g;
      v4i pf = *(const v4i*)(sm + PATLS + w*2048 + koff(m, k0));
      #pragma unroll
      for (int nt = 0; nt < 4; ++nt){
        v4i vf = *(const v4i*)(sm + VTLS + koff(nt*16 + m, k0));
        av[nt] = mfma16(pf, vf, av[nt]);
      }
    }
    #pragma unroll
    for (int nt = 0; nt < 4; ++nt) av[nt] = accfence(av[nt]);
    #pragma unroll
    for (int nt = 0; nt < 4; ++nt){
      #pragma unroll
      for (int j = 0; j < 4; ++j){
        *(unsigned short*)(sm + PATLS + w*2048 + koff(4*g + j, nt*16 + m)) = f2bf(av[nt][j]);
      }
    }
    __syncthreads();

    // sa += att_head @ Wproj[64*hh:64*hh+64, :]; wave w owns cols w*64..w*64+63
    #pragma unroll
    for (int ks = 0; ks < 2; ++ks){
      int k0 = ks*32 + 8*g;
      v4i af2[4];
      #pragma unroll
      for (int rt = 0; rt < 4; ++rt) af2[rt] = *(const v4i*)(sm + PATLS + rt*2048 + koff(m, k0));
      #pragma unroll
      for (int nt = 0; nt < 4; ++nt){
        v4i bp = *(const v4i*)(wpT + (w*64 + nt*16 + m)*256 + hh*64 + k0);
        #pragma unroll
        for (int rt = 0; rt < 4; ++rt) sa[rt][nt] = mfma16(af2[rt], bp, sa[rt][nt]);
      }
    }
    __syncthreads();
  }

  // ---------------- Phase C: x2 = x + sa + bproj; LN2 -> h2 ----------------
  {
    #pragma unroll
    for (int i = 0; i < 4; ++i){
      #pragma unroll
      for (int j = 0; j < 4; ++j) sa[i][j] = accfence(sa[i][j]);
    }
    float bp4[4], lg2[4], lb2[4];
    #pragma unroll
    for (int nt = 0; nt < 4; ++nt){
      int cc = w*64 + nt*16 + m;
      bp4[nt] = bpj[cc]; lg2[nt] = ln2g[cc]; lb2[nt] = ln2b[cc];
    }
    #pragma unroll
    for (int rt = 0; rt < 4; ++rt){
      #pragma unroll
      for (int j = 0; j < 4; ++j){
        int row = rt*16 + 4*g + j;
        #pragma unroll
        for (int nt = 0; nt < 4; ++nt){
          int col = w*64 + nt*16 + m;
          float v = xb[row*256 + col] + sa[rt][nt][j] + bp4[nt];
          sa[rt][nt][j] = v;
          outb[row*256 + col] = v;     // park x2 in d_out; re-read at final residual
        }
      }
    }
    #pragma unroll
    for (int rt = 0; rt < 4; ++rt){
      #pragma unroll
      for (int j = 0; j < 4; ++j){
        float s = 0.f, q = 0.f;
        #pragma unroll
        for (int nt = 0; nt < 4; ++nt){ float v = sa[rt][nt][j]; s += v; q += v*v; }
        s = rsum16(s); q = rsum16(q);
        if (m == 0){
          int row = rt*16 + 4*g + j;
          *(float*)(sm + PSUM + (w*64 + row)*4) = s;
          *(float*)(sm + PSQ  + (w*64 + row)*4) = q;
        }
      }
    }
    __syncthreads();
    if (tid < 64){
      float s = 0.f, q = 0.f;
      #pragma unroll
      for (int i = 0; i < 4; ++i){
        s += *(const float*)(sm + PSUM + (i*64 + tid)*4);
        q += *(const float*)(sm + PSQ  + (i*64 + tid)*4);
      }
      float mu = s * (1.f/256.f);
      float rs = rsqrtf(q * (1.f/256.f) - mu*mu + 1e-6f);
      *(float*)(sm + MU2 + tid*4) = mu;
      *(float*)(sm + RS2 + tid*4) = rs;
    }
    __syncthreads();
    #pragma unroll
    for (int rt = 0; rt < 4; ++rt){
      #pragma unroll
      for (int j = 0; j < 4; ++j){
        int row = rt*16 + 4*g + j;
        float mu = *(const float*)(sm + MU2 + row*4);
        float rs = *(const float*)(sm + RS2 + row*4);
        #pragma unroll
        for (int nt = 0; nt < 4; ++nt){
          int col = w*64 + nt*16 + m;
          float h2 = (sa[rt][nt][j] - mu) * rs * lg2[nt] + lb2[nt];
          *(unsigned short*)(sm + HLS + hoff(row, col)) = f2bf(h2);
        }
      }
    }
  }
  __syncthreads();

  // ---------------- Phase D: MLP, K-chunked; ff accumulates in regs ----------------
  v4f ff[4][4];
  #pragma unroll
  for (int i = 0; i < 4; ++i){
    #pragma unroll
    for (int j = 0; j < 4; ++j) ff[i][j] = zf;
  }

  #pragma unroll 1
  for (int ch = 0; ch < 4; ++ch){
    v4f a1[4][4];
    #pragma unroll
    for (int i = 0; i < 4; ++i){
      #pragma unroll
      for (int j = 0; j < 4; ++j) a1[i][j] = zf;
    }
    #pragma unroll
    for (int ks = 0; ks < 8; ++ks){
      int k0 = ks*32 + 8*g;
      v4i af[4];
      #pragma unroll
      for (int rt = 0; rt < 4; ++rt) af[rt] = *(const v4i*)(sm + HLS + hoff(rt*16 + m, k0));
      #pragma unroll
      for (int nt = 0; nt < 4; ++nt){
        v4i bw = *(const v4i*)(w1T + (ch*256 + w*64 + nt*16 + m)*256 + k0);
        #pragma unroll
        for (int rt = 0; rt < 4; ++rt) a1[rt][nt] = mfma16(af[rt], bw, a1[rt][nt]);
      }
    }
    float b1v[4];
    #pragma unroll
    for (int nt = 0; nt < 4; ++nt) b1v[nt] = b1[ch*256 + w*64 + nt*16 + m];
    #pragma unroll
    for (int i = 0; i < 4; ++i){
      #pragma unroll
      for (int j = 0; j < 4; ++j) a1[i][j] = accfence(a1[i][j]);
    }
    #pragma unroll
    for (int rt = 0; rt < 4; ++rt){
      #pragma unroll
      for (int j = 0; j < 4; ++j){
        int row = rt*16 + 4*g + j;
        #pragma unroll
        for (int nt = 0; nt < 4; ++nt){
          int cc = w*64 + nt*16 + m;
          float v = fmaxf(a1[rt][nt][j] + b1v[nt], 0.f);
          *(unsigned short*)(sm + ALS + hoff(row, cc)) = f2bf(v);
        }
      }
    }
    __syncthreads();
    #pragma unroll
    for (int ks = 0; ks < 8; ++ks){
      int k0 = ks*32 + 8*g;
      v4i af[4];
      #pragma unroll
      for (int rt = 0; rt < 4; ++rt) af[rt] = *(const v4i*)(sm + ALS + hoff(rt*16 + m, k0));
      #pragma unroll
      for (int nt = 0; nt < 4; ++nt){
        v4i bw = *(const v4i*)(w2T + (w*64 + nt*16 + m)*1024 + ch*256 + k0);
        #pragma unroll
        for (int rt = 0; rt < 4; ++rt) ff[rt][nt] = mfma16(af[rt], bw, ff[rt][nt]);
      }
    }
    __syncthreads();
  }

  {
    float b2v[4];
    #pragma unroll
    for (int nt = 0; nt < 4; ++nt) b2v[nt] = b2[w*64 + nt*16 + m];
    #pragma unroll
    for (int i = 0; i < 4; ++i){
      #pragma unroll
      for (int j = 0; j < 4; ++j) ff[i][j] = accfence(ff[i][j]);
    }
    #pragma unroll
    for (int rt = 0; rt < 4; ++rt){
      #pragma unroll
      for (int j = 0; j < 4; ++j){
        int row = rt*16 + 4*g + j;
        #pragma unroll
        for (int nt = 0; nt < 4; ++nt){
          int col = w*64 + nt*16 + m;
          outb[row*256 + col] += ff[rt][nt][j] + b2v[nt];
        }
      }
    }
  }
}

extern "C" void kernel_launch(void* const* d_in, const int* in_sizes, int n_in,
                              void* d_out, int out_size, void* d_ws, size_t ws_size,
                              hipStream_t stream) {
  const float* x    = (const float*)d_in[0];
  const float* ln1g = (const float*)d_in[1];
  const float* ln1b = (const float*)d_in[2];
  const float* Wq   = (const float*)d_in[3];
  const float* Wk   = (const float*)d_in[4];
  const float* Wv   = (const float*)d_in[5];
  const float* Wp   = (const float*)d_in[6];
  const float* bpj  = (const float*)d_in[7];
  const float* ln2g = (const float*)d_in[8];
  const float* ln2b = (const float*)d_in[9];
  const float* W1   = (const float*)d_in[10];
  const float* b1   = (const float*)d_in[11];
  const float* W2   = (const float*)d_in[12];
  const float* b2   = (const float*)d_in[13];
  unsigned short* ws = (unsigned short*)d_ws;

  prep_w<<<3072, 256, 0, stream>>>(Wq, Wk, Wv, Wp, W1, W2, ws);
  blk_fwd<<<4096, 256, 0, stream>>>(x, ln1g, ln1b,
                                    ws, ws + 65536, ws + 131072, ws + 196608,
                                    bpj, ln2g, ln2b,
                                    ws + 262144, b1, ws + 524288, b2,
                                    (float*)d_out);
}